// Round 8
// baseline (168.218 us; speedup 1.0000x reference)
//
#include <hip/hip_runtime.h>
#include <hip/hip_bf16.h>

typedef __attribute__((ext_vector_type(8))) short short8;
typedef __attribute__((ext_vector_type(4))) float f32x4;

#define NPOS  65536
#define NOUT  16777216
#define QCAP  240
#define DELTA 0.05f

// ---------------------------------------------------------------------------
// Kernel 1: normalize prototypes, write pnN f32 [p][k] and bf16 copy.
// ---------------------------------------------------------------------------
__global__ __launch_bounds__(256) void proto_prep(
    const float* __restrict__ proto, float* __restrict__ pnN,
    ushort* __restrict__ pnBF) {
  int p = blockIdx.x;       // 0..511
  int c = threadIdx.x;      // 0..255
  float v = proto[p * 256 + c];
  float s = v * v;
  #pragma unroll
  for (int off = 32; off > 0; off >>= 1) s += __shfl_down(s, off);
  __shared__ float red[4];
  int lane = c & 63, wid = c >> 6;
  if (lane == 0) red[wid] = s;
  __syncthreads();
  float tot = red[0] + red[1] + red[2] + red[3];
  float nrm = fmaxf(sqrtf(tot), 1e-12f);
  float q = v / nrm;
  pnN[p * 256 + c] = q;
  __hip_bfloat16 h = __float2bfloat16(q);
  pnBF[p * 256 + c] = *reinterpret_cast<ushort*>(&h);
}

// ---------------------------------------------------------------------------
// Kernel 2: round-7 logic with round-4's high-MLP staging, improved:
// ALL 8 float4 loads per thread issued up front (64 KB/block in flight;
// round-7's global_load_lds had 8 KB -> 365 GB/s read rate, the regression).
// Two raw-f32 convert phases (32 KB raw union), then the validated
// mq-loop + cnt-skip rescore + packed-atomicMax tail.
// ---------------------------------------------------------------------------
__global__ __launch_bounds__(512, 2) void match_kernel(
    const float* __restrict__ x, const float* __restrict__ proto,
    const float* __restrict__ pnN, const ushort* __restrict__ pnBF,
    float* __restrict__ out) {
  __shared__ __align__(16) ushort xbf[64 * 256];   // 32 KB bf16 [m][k] swizzled
  __shared__ __align__(16) union UU {
    float raw[128 * 64];                           // 32 KB f32 (half-K staging)
    struct {
      float wmax[8][16];
      float thr[16];
      int   queue[QCAP];
      unsigned long long b64[64];
      int   idxl[64];
      int   cnt[64];
      int   qn;
    } s;
  } u;

  const int t = threadIdx.x;
  const int l = t & 63, w = t >> 6;
  const int g = l >> 4, c16 = l & 15, r8 = l & 7;
  const int n0 = blockIdx.x << 6;
  const int b = n0 >> 10, hw0 = n0 & 1023;
  const float* xg = x + ((size_t)b << 18) + hw0;   // + k*1024 + pos

  // ---- prefetch entire 64KB x-tile: 8 independent float4 loads/thread ----
  float4 v[8];
  #pragma unroll
  for (int i = 0; i < 8; ++i) {
    int q = t + (i << 9);
    int krel = q >> 4;                 // 0..255
    int m4 = (q & 15) << 2;
    v[i] = *reinterpret_cast<const float4*>(xg + (krel << 10) + m4);
  }

  // ---- two convert phases: regs -> raw f32 -> xbf bf16 (transposed) ----
  #pragma unroll 1
  for (int ph = 0; ph < 2; ++ph) {
    #pragma unroll
    for (int i = 0; i < 4; ++i) {
      int q = t + (i << 9);
      int krel = q >> 4;               // row within half: 0..127
      int m4 = (q & 15) << 2;
      *reinterpret_cast<float4*>(&u.raw[(krel << 6) + m4]) = v[(ph << 2) + i];
    }
    __syncthreads();
    #pragma unroll
    for (int i = 0; i < 2; ++i) {
      int q = t + (i << 9);
      int m = q & 63, cR = q >> 6;     // cR 0..15: 8-k chunk within half
      short8 pk;
      #pragma unroll
      for (int j = 0; j < 8; ++j) {
        float f = u.raw[(((cR << 3) + j) << 6) + m];
        __hip_bfloat16 h = __float2bfloat16(f);
        pk[j] = *reinterpret_cast<short*>(&h);
      }
      int chunk = (ph << 4) + cR;      // absolute 16B (8-k) chunk 0..31
      int dst = (m << 8) + ((chunk ^ (m & 7)) << 3);
      *reinterpret_cast<short8*>(&xbf[dst]) = pk;
    }
    __syncthreads();
  }

  if (t == 0) u.s.qn = 0;
  if (t < 64) { u.s.cnt[t] = 0; u.s.b64[t] = 0ULL; }  // raw dead; barriers below

  const ushort* pB0 = pnBF + (((w << 6) + c16) << 8) + (g << 3);

  // ---- 4 m-quarters of 16 positions each ----
  #pragma unroll 1
  for (int mq = 0; mq < 4; ++mq) {
    f32x4 acc[4];
    #pragma unroll
    for (int ni = 0; ni < 4; ++ni) acc[ni] = (f32x4){0.f, 0.f, 0.f, 0.f};

    #pragma unroll
    for (int ks = 0; ks < 8; ++ks) {
      const short8 a = *reinterpret_cast<const short8*>(
          &xbf[(((mq << 4) + c16) << 8) + ((((ks << 2) + g) ^ r8) << 3)]);
      #pragma unroll
      for (int ni = 0; ni < 4; ++ni) {
        const short8 bf = *reinterpret_cast<const short8*>(
            pB0 + (ni << 12) + (ks << 5));
        acc[ni] = __builtin_amdgcn_mfma_f32_16x16x32_bf16(a, bf, acc[ni], 0, 0, 0);
      }
    }

    // per-pos max over 512 protos
    #pragma unroll
    for (int r = 0; r < 4; ++r) {
      float m = fmaxf(fmaxf(acc[0][r], acc[1][r]), fmaxf(acc[2][r], acc[3][r]));
      #pragma unroll
      for (int s = 1; s < 16; s <<= 1) m = fmaxf(m, __shfl_xor(m, s));
      if (c16 == 0) u.s.wmax[w][(g << 2) + r] = m;
    }
    __syncthreads();
    if (t < 16) {
      float bm = u.s.wmax[0][t];
      #pragma unroll
      for (int ww = 1; ww < 8; ++ww) bm = fmaxf(bm, u.s.wmax[ww][t]);
      u.s.thr[t] = bm - DELTA;
    }
    __syncthreads();
    #pragma unroll
    for (int ni = 0; ni < 4; ++ni)
      #pragma unroll
      for (int r = 0; r < 4; ++r) {
        int p16 = (g << 2) + r;
        if (acc[ni][r] >= u.s.thr[p16]) {
          int pos = (mq << 4) + p16;
          int slot = atomicAdd(&u.s.qn, 1);
          atomicAdd(&u.s.cnt[pos], 1);
          if (slot < QCAP)
            u.s.queue[slot] = (((w << 6) + (ni << 4) + c16) << 6) | pos;
        }
      }
    __syncthreads();   // protects wmax/thr reuse next mq
  }

  // ---- resolve: cnt==1 -> direct; cnt>1 -> exact fp32 rescore + atomicMax --
  int n = u.s.qn < QCAP ? u.s.qn : QCAP;
  for (int j = t; j < n; j += 512) {
    int e = u.s.queue[j];
    int pos = e & 63, p = e >> 6;
    if (u.s.cnt[pos] == 1) {
      u.s.idxl[pos] = p;               // sole candidate == argmax
    } else {
      float a = 0.f;                   // exact sequential fmaf (validated)
      const float* pr = pnN + (p << 8);
      for (int k = 0; k < 256; ++k)
        a = fmaf(xg[(k << 10) + pos], pr[k], a);
      unsigned int ub = __float_as_uint(a);
      ub ^= (unsigned int)(((int)ub >> 31)) | 0x80000000u;  // orderable
      unsigned long long key =
          ((unsigned long long)ub << 32) | (unsigned long long)(511 - p);
      atomicMax(&u.s.b64[pos], key);   // ties: larger (511-p) => smaller p
    }
  }
  __syncthreads();

  // ---- write indices ----
  if (t < 64) {
    int bp = (u.s.cnt[t] == 1) ? u.s.idxl[t]
                               : 511 - (int)(u.s.b64[t] & 511ULL);
    u.s.idxl[t] = bp;
    out[(size_t)NOUT + n0 + t] = (float)bp;
  }
  __syncthreads();

  // ---- recon gather: out[b][c][hw0+pos] = proto[idx[pos]][c] ----
  float* rb = out + ((size_t)b << 18) + hw0;
  #pragma unroll 1
  for (int it = 0; it < 32; ++it) {
    int lin = (it << 9) + t;
    int c = lin >> 6, pos = lin & 63;
    rb[((size_t)c << 10) + pos] = proto[(u.s.idxl[pos] << 8) + c];
  }
}

extern "C" void kernel_launch(void* const* d_in, const int* in_sizes, int n_in,
                              void* d_out, int out_size, void* d_ws, size_t ws_size,
                              hipStream_t stream) {
  const float* x = (const float*)d_in[0];        // (64, 256, 32, 32) f32
  const float* proto = (const float*)d_in[1];    // (512, 256) f32
  float* out = (float*)d_out;                    // 16777216 recon + 65536 idx
  float* pnN = (float*)d_ws;                     // 512*256 f32 = 512 KB
  ushort* pnBF = (ushort*)((char*)d_ws + 512 * 256 * sizeof(float)); // 256 KB

  proto_prep<<<512, 256, 0, stream>>>(proto, pnN, pnBF);
  match_kernel<<<NPOS / 64, 512, 0, stream>>>(x, proto, pnN, pnBF, out);
}